// Round 12
// baseline (101.352 us; speedup 1.0000x reference)
//
#include <hip/hip_runtime.h>
#include <hip/hip_bf16.h>

typedef __attribute__((ext_vector_type(8))) short short8;
typedef __attribute__((ext_vector_type(4))) float float4v;

typedef __attribute__((address_space(3))) unsigned int lds_u32;
typedef __attribute__((address_space(1))) const unsigned int glb_u32;

__device__ __forceinline__ unsigned short f2bf(float f) {
    // round-to-nearest-even fp32 -> bf16
    unsigned int u = __builtin_bit_cast(unsigned int, f);
    unsigned int lsb = (u >> 16) & 1u;
    u += 0x7fffu + lsb;
    return (unsigned short)(u >> 16);
}

__device__ __forceinline__ unsigned int pack2(float f0, float f1) {
    // round-half-up fp32x2 -> packed bf16x2
    unsigned int u0 = __builtin_bit_cast(unsigned int, f0) + 0x8000u;
    unsigned int u1 = __builtin_bit_cast(unsigned int, f1) + 0x8000u;
    return (u0 >> 16) | (u1 & 0xffff0000u);
}

// ---------------------------------------------------------------------------
// prep (proven, R8): LN + projections (MFMA) and woT build.
// b_out stored with XOR-swizzled k-octets so fused's linear global_load_lds
// yields conflict-free ds_read_b128 b-fragments.
// NOTE (R9-R11): cooperative-kernel merge hung the container (grid.sync
// under graph capture); subsequent identical-to-R8 resubmits failed on what
// is diagnosed as a wedged node (kernel audited race-free; deterministic
// binary passed cleanly in R8 at 100.5 us / absmax 3.9e-3).
// ---------------------------------------------------------------------------
__global__ __launch_bounds__(128) void prep(
    const float* __restrict__ msa, const float* __restrict__ ln_w,
    const float* __restrict__ ln_b, const float* __restrict__ wa,
    const float* __restrict__ ba, const float* __restrict__ wb,
    const float* __restrict__ bb, const float* __restrict__ wo,
    unsigned short* __restrict__ a_out, unsigned short* __restrict__ b_out,
    unsigned short* __restrict__ woT)
{
    const int b = blockIdx.x;
    if (b >= 512) {                       // ---- woT transpose/convert ----
        const int idx = (b - 512) * 128 + threadIdx.x;
        const int hk = idx >> 6, p = idx & 63;
        const int h = hk >> 5, k = hk & 31;
        woT[(size_t)p * 1024 + k * 32 + h] = f2bf(wo[idx]);
        return;
    }

    __shared__ __align__(16) unsigned short xn[2][16 * 72];
    const int n = b >> 1;
    const int w = threadIdx.x >> 6;
    const int lane = threadIdx.x & 63;
    const int s0 = (b & 1) * 32 + w * 16;
    const int sl = lane >> 2, dg = lane & 3;
    const int lm = lane & 15, q = lane >> 4;

    const float* __restrict__ row = msa + ((size_t)((s0 + sl) * 256 + n)) * 64;
    float4 x[4];
    #pragma unroll
    for (int ii = 0; ii < 4; ++ii) x[ii] = *(const float4*)(row + ii * 16 + dg * 4);

    float s = 0.f;
    #pragma unroll
    for (int ii = 0; ii < 4; ++ii) s += (x[ii].x + x[ii].y) + (x[ii].z + x[ii].w);
    s += __shfl_xor(s, 1, 4);
    s += __shfl_xor(s, 2, 4);
    const float mu = s * (1.f / 64.f);

    float v = 0.f;
    #pragma unroll
    for (int ii = 0; ii < 4; ++ii) {
        float a0 = x[ii].x - mu, a1 = x[ii].y - mu, a2 = x[ii].z - mu, a3 = x[ii].w - mu;
        v += (a0 * a0 + a1 * a1) + (a2 * a2 + a3 * a3);
    }
    v += __shfl_xor(v, 1, 4);
    v += __shfl_xor(v, 2, 4);
    const float rs = rsqrtf(v * (1.f / 64.f) + 1e-5f);

    #pragma unroll
    for (int ii = 0; ii < 4; ++ii) {
        const float4 lw = *(const float4*)(ln_w + ii * 16 + dg * 4);
        const float4 lb = *(const float4*)(ln_b + ii * 16 + dg * 4);
        uint2 pk;
        pk.x = pack2((x[ii].x - mu) * rs * lw.x + lb.x, (x[ii].y - mu) * rs * lw.y + lb.y);
        pk.y = pack2((x[ii].z - mu) * rs * lw.z + lb.z, (x[ii].w - mu) * rs * lw.w + lb.w);
        *(uint2*)(&xn[w][sl * 72 + ii * 16 + dg * 4]) = pk;
    }
    __syncthreads();

    short8 afr[2];
    #pragma unroll
    for (int ks = 0; ks < 2; ++ks)
        afr[ks] = *(const short8*)(&xn[w][lm * 72 + ks * 32 + q * 8]);

    float4v acc[4];
    #pragma unroll
    for (int c = 0; c < 4; ++c) acc[c] = (float4v){0.f, 0.f, 0.f, 0.f};
    #pragma unroll
    for (int c = 0; c < 4; ++c) {
        const int hp = c * 16 + lm;
        const float* __restrict__ wsrc = (hp < 32) ? (wa + hp) : (wb + hp - 32);
        #pragma unroll
        for (int ks = 0; ks < 2; ++ks) {
            short8 bfr;
            #pragma unroll
            for (int j = 0; j < 8; ++j)
                bfr[j] = (short)f2bf(wsrc[(ks * 32 + q * 8 + j) * 32]);
            acc[c] = __builtin_amdgcn_mfma_f32_16x16x32_bf16(afr[ks], bfr, acc[c], 0, 0, 0);
        }
    }

    #pragma unroll
    for (int c = 0; c < 4; ++c) {
        const int hp = c * 16 + lm;
        const float bias = (hp < 32) ? ba[hp] : bb[hp - 32];
        const float scale = (hp < 32) ? (1.f / 64.f) : 1.f;  // fold 1/S into a
        uint2 pk;
        pk.x = pack2((acc[c][0] + bias) * scale, (acc[c][1] + bias) * scale);
        pk.y = pack2((acc[c][2] + bias) * scale, (acc[c][3] + bias) * scale);
        const int sbase = s0 + q * 4;
        if (hp < 32) {
            *(uint2*)(a_out + ((size_t)(n * 32 + hp)) * 64 + sbase) = pk;
        } else {
            const int R = n * 32 + (hp - 32);
            const int o = sbase >> 3;
            const int phys = (R << 6) + (((o ^ (R & 7)) << 3) | (sbase & 7));
            *(uint2*)(b_out + phys) = pk;
        }
    }
}

// ---------------------------------------------------------------------------
// fused_opm v8 (best measured: total 100.5 us): producer/consumer pipeline
// with LDS-traffic cuts. Per-tile LDS traffic ~144 KB (fill 16 + B 32 +
// Mw 32 + Mr 32 + R 32) — at the ds_read_b128 throughput bound.
//   producers (waves 0-3): 2x2 tiling — wave w computes rows
//     [(w>>1)*64, +64) x cols [(w&1)*64, +64); 32 MFMAs/wave; C packed bf16
//     to double-buffered ldsM (pair stride 1272).
//   consumers (waves 4-7): async ldsB fills (pre-swizzled, linear
//     global_load_lds) + k-split x4 stage2 — wave cw contracts
//     k in [cw*8,cw*8+8) for ALL 64 p (M read ONCE per tile); fp32 partials
//     -> dense double-buffered ldsR; reduced 2 tiles later -> out.
// Uniform 18-iteration loop, one barrier per iteration, guards select work:
//   iter t: fill(t+1) | stage1(t) | stage2(t-1)->ldsR | reduce(t-2)->out.
// Buffer hazards (all 2-deep, disjoint windows, barrier-separated):
// B[t] w(t-1,t) r(t,t+1); M[t] w(t,t+1) r(t+1,t+2); R[t] w(t+1,t+2)
// r(t+2,t+3). Barrier counts equal by construction (19/19).
// LDS 143.5 KB -> 1 block/CU; ~190 regs/path, no spill.
// launch_bounds(512,2): 256-reg cap (R6 lesson: never cap below the wf
// working set — (256,3) spilled 90 MB to scratch).
// ---------------------------------------------------------------------------
__global__ __launch_bounds__(512, 2) void fused_opm(
    const unsigned short* __restrict__ a_b, const unsigned short* __restrict__ b_swz,
    const unsigned short* __restrict__ woT, const float* __restrict__ bo,
    float* __restrict__ out)
{
    __shared__ __align__(16) unsigned short ldsB[2][8192];      // 32 KB
    __shared__ __align__(16) unsigned short ldsM[2][16 * 1272]; // 79.5 KB
    __shared__ __align__(16) float ldsR[2][4096];               // 32 KB

    const int b = blockIdx.x;
    const int bi = b >> 2;
    const int bj0 = (b & 3) << 4;        // 16 tiles per block
    const int wv = threadIdx.x >> 6;
    const int lane = threadIdx.x & 63;
    const int lm = lane & 15, q = lane >> 4;

    if (wv < 4) {
        // ==================== PRODUCERS: stage 1 (2x2 tiling) ====================
        const int wr = wv >> 1;           // row-half: i_loc in {2wr, 2wr+1}
        const int wc = wv & 1;            // col-half: j_loc in {2wc, 2wc+1}

        short8 af[4][2];                  // rows bi*128 + wr*64 + r*16 + lm
        #pragma unroll
        for (int r = 0; r < 4; ++r)
            #pragma unroll
            for (int ks = 0; ks < 2; ++ks)
                af[r][ks] = *(const short8*)(a_b + ((size_t)(bi * 128 + wr * 64 + r * 16 + lm)) * 64 + ks * 32 + q * 8);

        __syncthreads();                  // bar0: consumers' fill(0) drained

        for (int t = 0; t < 18; ++t) {
            if (t < 16) {
                const unsigned short* __restrict__ B = ldsB[t & 1];
                unsigned short* __restrict__ M = ldsM[t & 1];

                short8 bf[4][2];
                #pragma unroll
                for (int c = 0; c < 4; ++c)
                    #pragma unroll
                    for (int ks = 0; ks < 2; ++ks) {
                        const int rrow = wc * 64 + c * 16 + lm;
                        const int o = ks * 4 + q;               // k-octet
                        bf[c][ks] = *(const short8*)(&B[(rrow << 6) + ((o ^ (rrow & 7)) << 3)]);
                    }
                float4v acc1[4][4];
                #pragma unroll
                for (int r = 0; r < 4; ++r)
                    #pragma unroll
                    for (int c = 0; c < 4; ++c) acc1[r][c] = (float4v){0.f, 0.f, 0.f, 0.f};
                #pragma unroll
                for (int c = 0; c < 4; ++c)
                    #pragma unroll
                    for (int ks = 0; ks < 2; ++ks)
                        #pragma unroll
                        for (int r = 0; r < 4; ++r)
                            acc1[r][c] = __builtin_amdgcn_mfma_f32_16x16x32_bf16(af[r][ks], bf[c][ks], acc1[r][c], 0, 0, 0);

                // C row = wr*64 + r*16 + q*4+e -> i_loc = 2wr + (r>>1), h = (r&1)*16+q*4+e
                // C col = wc*64 + c*16 + lm   -> j_loc = 2wc + (c>>1), k = (c&1)*16+lm
                #pragma unroll
                for (int r = 0; r < 4; ++r)
                    #pragma unroll
                    for (int c = 0; c < 4; ++c) {
                        const int pair = (2 * wr + (r >> 1)) * 4 + 2 * wc + (c >> 1);
                        const int k = ((c & 1) << 4) + lm;
                        const int h0 = ((r & 1) << 4) + q * 4;
                        uint2 pk;
                        pk.x = pack2(acc1[r][c][0], acc1[r][c][1]);
                        pk.y = pack2(acc1[r][c][2], acc1[r][c][3]);
                        *(uint2*)(M + pair * 1272 + k * 40 + h0) = pk;
                    }
            }
            __syncthreads();              // bar(t+1)
        }
    } else {
        // ==================== CONSUMERS: fills + k-split stage 2 + reduce ====================
        const int cw = wv - 4;            // k-slice [cw*8, cw*8+8) and reduce p-tile cw

        auto fill = [&](int tt) {         // async 16 KB b-tile (bj0+tt) -> ldsB[tt&1]
            #pragma unroll
            for (int li = 0; li < 4; ++li) {
                const int chunk = cw * 4 + li;                  // 16 x 1 KB chunks
                const unsigned short* g = b_swz + (size_t)(bj0 + tt) * 8192 + chunk * 512 + lane * 8;
                __builtin_amdgcn_global_load_lds((glb_u32*)g,
                    (lds_u32*)(&ldsB[tt & 1][chunk * 512]), 16, 0, 0);
            }
        };

        short8 wf[4][8];                  // woT rows p = mt*16+lm, k = cw*8+ks
        #pragma unroll
        for (int mt = 0; mt < 4; ++mt)
            #pragma unroll
            for (int ks = 0; ks < 8; ++ks)
                wf[mt][ks] = *(const short8*)(woT + ((size_t)(mt * 16 + lm)) * 1024 + (cw * 8 + ks) * 32 + q * 8);

        const float4 bo4 = *(const float4*)(bo + cw * 16 + q * 4);
        const int i = bi * 4 + (lm >> 2);
        const int jb = lm & 3;

        fill(0);
        __syncthreads();                  // bar0

        for (int t = 0; t < 18; ++t) {
            if (t + 1 < 16) fill(t + 1);

            if (t >= 1 && t <= 16) {      // stage2(t-1): partials for tile t-1
                const int tt = t - 1;
                const unsigned short* __restrict__ M = ldsM[tt & 1];
                float4v acc2[4];
                #pragma unroll
                for (int mt = 0; mt < 4; ++mt) acc2[mt] = (float4v){0.f, 0.f, 0.f, 0.f};
                #pragma unroll
                for (int ks = 0; ks < 8; ++ks) {
                    const short8 mf = *(const short8*)(M + lm * 1272 + (cw * 8 + ks) * 40 + q * 8);
                    #pragma unroll
                    for (int mt = 0; mt < 4; ++mt)
                        acc2[mt] = __builtin_amdgcn_mfma_f32_16x16x32_bf16(wf[mt][ks], mf, acc2[mt], 0, 0, 0);
                }
                float* __restrict__ R = ldsR[tt & 1];
                #pragma unroll
                for (int mt = 0; mt < 4; ++mt)
                    *(float4v*)(&R[((cw * 4 + mt) << 8) + (lane << 2)]) = acc2[mt];
            }

            if (t >= 2) {                 // reduce(t-2): p-tile cw, all k-slices
                const int tt = t - 2;
                const float* __restrict__ R = ldsR[tt & 1];
                float4v sum = *(const float4v*)(&R[(cw << 8) + (lane << 2)]);
                #pragma unroll
                for (int kh = 1; kh < 4; ++kh)
                    sum += *(const float4v*)(&R[((kh * 4 + cw) << 8) + (lane << 2)]);
                const int j = (bj0 + tt) * 4 + jb;
                float4 o;
                o.x = sum[0] + bo4.x;
                o.y = sum[1] + bo4.y;
                o.z = sum[2] + bo4.z;
                o.w = sum[3] + bo4.w;
                *(float4*)(out + ((size_t)(i * 256 + j)) * 64 + cw * 16 + q * 4) = o;
            }
            __syncthreads();              // bar(t+1)
        }
    }
}

// ---------------------------------------------------------------------------
extern "C" void kernel_launch(void* const* d_in, const int* in_sizes, int n_in,
                              void* d_out, int out_size, void* d_ws, size_t ws_size,
                              hipStream_t stream) {
    const float* msa  = (const float*)d_in[0];
    const float* ln_w = (const float*)d_in[1];
    const float* ln_b = (const float*)d_in[2];
    const float* wa   = (const float*)d_in[3];
    const float* ba   = (const float*)d_in[4];
    const float* wb   = (const float*)d_in[5];
    const float* bb   = (const float*)d_in[6];
    const float* wo   = (const float*)d_in[7];
    const float* bo   = (const float*)d_in[8];
    float* out = (float*)d_out;

    // workspace (bf16): a (1 MB) | b (1 MB, octet-swizzled) | woT (128 KB)
    unsigned short* a_ws = (unsigned short*)d_ws;
    unsigned short* b_ws = a_ws + 256 * 32 * 64;
    unsigned short* woT  = b_ws + 256 * 32 * 64;

    prep<<<1024, 128, 0, stream>>>(msa, ln_w, ln_b, wa, ba, wb, bb, wo, a_ws, b_ws, woT);
    fused_opm<<<256, 512, 0, stream>>>(a_ws, b_ws, woT, bo, out);
}